// Round 20
// baseline (307.755 us; speedup 1.0000x reference)
//
#include <hip/hip_runtime.h>

typedef __attribute__((ext_vector_type(8))) short bf16x8;
typedef __attribute__((ext_vector_type(4))) float f32x4;
typedef __attribute__((ext_vector_type(16))) float f32x16;

__device__ __forceinline__ unsigned short f2bf(float f) {
  unsigned int u = __float_as_uint(f);
  u += 0x7FFF + ((u >> 16) & 1);
  return (unsigned short)(u >> 16);
}

__device__ __forceinline__ void gload_lds16(const void* g, void* l) {
  __builtin_amdgcn_global_load_lds(
      (const __attribute__((address_space(1))) unsigned int*)g,
      (__attribute__((address_space(3))) unsigned int*)l,
      16, 0, 0);
}

#define MF(a, b, c) __builtin_amdgcn_mfma_f32_16x16x32_bf16((a), (b), (c), 0, 0, 0)
#define MF32(a, b, c) __builtin_amdgcn_mfma_f32_32x32x16_bf16((a), (b), (c), 0, 0, 0)
#define FENCE asm volatile("" ::: "memory")

// ---------------------------------------------------------------------------
// fused cast fp32 -> bf16
// ---------------------------------------------------------------------------
__global__ void cast_all(const float* __restrict__ x,
                         const float* __restrict__ wa,
                         const float* __restrict__ wp,
                         unsigned short* __restrict__ xb,
                         unsigned short* __restrict__ wab,
                         unsigned short* __restrict__ wpb,
                         int n1, int n2, int n4) {
  int stride = gridDim.x * blockDim.x;
  for (int i = blockIdx.x * blockDim.x + threadIdx.x; i < n4; i += stride) {
    const float4* src;
    ushort4* dst;
    int j;
    if (i < n1)      { src = (const float4*)x,  dst = (ushort4*)xb,  j = i; }
    else if (i < n2) { src = (const float4*)wa, dst = (ushort4*)wab, j = i - n1; }
    else             { src = (const float4*)wp, dst = (ushort4*)wpb, j = i - n2; }
    float4 v = src[j];
    ushort4 o;
    o.x = f2bf(v.x); o.y = f2bf(v.y); o.z = f2bf(v.z); o.w = f2bf(v.w);
    dst[j] = o;
  }
}

// ---------------------------------------------------------------------------
// 128x256 GEMM v5: 32x32x16 MFMA, ONE phase per K=64 tile (32 phases/block,
// half of v4), triple-buffered LDS (A 3x16KB + B 3x32KB = 144KB) so the
// counted-vmcnt pipeline needs no drain: phase t reads buf[t%3], stages
// buf[(t+2)%3] <- tile t+2 (6 loads), vmcnt(6) retires phase t-1's stage
// (read at t+1), leaves own in flight. PH shape (stage->vmcnt->barrier->
// setprio MFMA->barrier) and 128B-row swizzle cb^=row&7 unchanged from the
// measured round-8/v4 template. Per wave: 64x64 out via 2x2 MFMAs of 32x32,
// K=64 per phase = 16 MFMA (32 KFLOP each).
// C/D layout (verified m74/m101): col=lane&31, row=(reg&3)+8(reg>>2)+4(lane>>5).
// Grid 24x32 = 768 blocks = exactly 3 rounds.
// ---------------------------------------------------------------------------
template<int EPI>
__global__ __launch_bounds__(512, 2)
void gemm8p(const unsigned short* __restrict__ A,
            const unsigned short* __restrict__ Bw,
            float* __restrict__ Cf,
            unsigned short* __restrict__ Qo,
            unsigned short* __restrict__ Ko,
            unsigned short* __restrict__ Vo,
            int M, int N, int K, int Lseq) {
  __shared__ unsigned short Al[3][128 * 64];  // 3 x 16KB
  __shared__ unsigned short Bl[3][256 * 64];  // 3 x 32KB
  const int tid = threadIdx.x;
  const int lane = tid & 63, w = tid >> 6;
  const int wm = w >> 2, wn = w & 3;          // 2 M-halves x 4 N-quarters
  const int l31 = lane & 31, l5 = lane >> 5;
  const int sa = l31 & 7;                     // row&7 for read swizzle
  const long arow0 = (long)blockIdx.y * 128;
  const long brow0 = (long)blockIdx.x * 256;

#define LDA32(p, mi, ks)                                                      \
  (*(const bf16x8*)((const char*)Al + (p)*16384 +                             \
                    ((wm * 64 + (mi)*32 + l31) << 7) +                        \
                    ((((ks)*2 + l5) ^ sa) << 4)))
#define LDB32(p, ni, ks)                                                      \
  (*(const bf16x8*)((const char*)Bl + (p)*32768 +                             \
                    ((wn * 64 + (ni)*32 + l31) << 7) +                        \
                    ((((ks)*2 + l5) ^ sa) << 4)))

#define STGA(pbuf, kt)                                                        \
  do {                                                                        \
    _Pragma("unroll")                                                         \
    for (int c_ = 0; c_ < 2; ++c_) {                                          \
      int off_ = (c_ << 13) + (tid << 4);                                     \
      int row_ = off_ >> 7;                                                   \
      int cbs_ = ((off_ >> 4) & 7) ^ (row_ & 7);                              \
      gload_lds16(A + (arow0 + row_) * (long)K + ((kt) << 6) + cbs_ * 8,      \
                  (char*)Al + (pbuf)*16384 + off_);                           \
    }                                                                         \
  } while (0)
#define STGB(pbuf, kt)                                                        \
  do {                                                                        \
    _Pragma("unroll")                                                         \
    for (int c_ = 0; c_ < 4; ++c_) {                                          \
      int off_ = (c_ << 13) + (tid << 4);                                     \
      int row_ = off_ >> 7;                                                   \
      int cbs_ = ((off_ >> 4) & 7) ^ (row_ & 7);                              \
      gload_lds16(Bw + (brow0 + row_) * (long)K + ((kt) << 6) + cbs_ * 8,     \
                  (char*)Bl + (pbuf)*32768 + off_);                           \
    }                                                                         \
  } while (0)

#define VM6 asm volatile("s_waitcnt vmcnt(6)" ::: "memory")

  f32x16 acc[2][2];
#pragma unroll
  for (int i = 0; i < 2; ++i)
#pragma unroll
    for (int j = 0; j < 2; ++j)
#pragma unroll
      for (int e = 0; e < 16; ++e) acc[i][j][e] = 0.f;

  const int NT = K >> 6;  // 32 K-tiles of 64
  // prologue: t0 -> buf0, t1 -> buf1; vmcnt(6) waits t0's 6, t1 in flight
  STGA(0, 0); STGB(0, 0);
  STGA(1, 1); STGB(1, 1);
  VM6;
  FENCE; __builtin_amdgcn_s_barrier(); FENCE;

  int p = 0;
  for (int t = 0; t < NT; ++t) {
    int ps = p + 2; if (ps >= 3) ps -= 3;
    int ts = t + 2; if (ts > NT - 1) ts = NT - 1;

    bf16x8 a[2][4], b[2][4];
#pragma unroll
    for (int ks = 0; ks < 4; ++ks) {
      a[0][ks] = LDA32(p, 0, ks);
      a[1][ks] = LDA32(p, 1, ks);
      b[0][ks] = LDB32(p, 0, ks);
      b[1][ks] = LDB32(p, 1, ks);
    }
    STGA(ps, ts); STGB(ps, ts);
    VM6;                               // retires phase t-1's stage (tile t+1)
    FENCE; __builtin_amdgcn_s_barrier(); FENCE;
    __builtin_amdgcn_s_setprio(1);
#pragma unroll
    for (int ks = 0; ks < 4; ++ks) {
      acc[0][0] = MF32(a[0][ks], b[0][ks], acc[0][0]);
      acc[0][1] = MF32(a[0][ks], b[1][ks], acc[0][1]);
      acc[1][0] = MF32(a[1][ks], b[0][ks], acc[1][0]);
      acc[1][1] = MF32(a[1][ks], b[1][ks], acc[1][1]);
    }
    __builtin_amdgcn_s_setprio(0);
    FENCE; __builtin_amdgcn_s_barrier(); FENCE;
    ++p; if (p == 3) p = 0;
  }
  asm volatile("s_waitcnt vmcnt(0)" ::: "memory");

  const float qscale = 0.08838834764831845f;  // 1/sqrt(128) folded into Q
#pragma unroll
  for (int mi = 0; mi < 2; ++mi) {
#pragma unroll
    for (int ni = 0; ni < 2; ++ni) {
#pragma unroll
      for (int reg = 0; reg < 16; ++reg) {
        long row = arow0 + wm * 64 + mi * 32 +
                   (reg & 3) + 8 * (reg >> 2) + 4 * l5;
        long col = brow0 + wn * 64 + ni * 32 + l31;
        float v = acc[mi][ni][reg];
        if (EPI == 0) {
          Cf[row * N + col] = v;
        } else {
          int which = (int)(col >> 11);
          int h = ((int)col >> 7) & 15;
          int d = (int)col & 127;
          int b_ = (int)(row >> 11);
          int l = (int)row & 2047;
          long bhead = (long)(b_ * 16 + h);
          if (which == 0)
            Qo[(bhead * Lseq + l) * 128 + d] = f2bf(v * qscale);
          else if (which == 1)
            Ko[(bhead * Lseq + l) * 128 + d] = f2bf(v);
          else
            Vo[(bhead * 128 + d) * Lseq + l] = f2bf(v);
        }
      }
    }
  }
#undef LDA32
#undef LDB32
#undef STGA
#undef STGB
#undef VM6
}

// ---------------------------------------------------------------------------
// 2-phase 128x128 GEMM (proj). Known-correct.
// ---------------------------------------------------------------------------
template<int EPI>
__global__ __launch_bounds__(256, 4)
void gemm_bt(const unsigned short* __restrict__ A,
             const unsigned short* __restrict__ Bw,
             float* __restrict__ Cf,
             unsigned short* __restrict__ Qo,
             unsigned short* __restrict__ Ko,
             unsigned short* __restrict__ Vo,
             int M, int N, int K, int Lseq, int nbx) {
  __shared__ unsigned short As[2][128 * 32];
  __shared__ unsigned short Bs[2][128 * 32];
  const int tid = threadIdx.x;
  const int lane = tid & 63, w = tid >> 6;
  const int wm = w >> 1, wn = w & 1;
  const int g4 = lane >> 4, r16 = lane & 15;

  const int nwg = gridDim.x;
  const int cpx = nwg >> 3;
  const int bid = (blockIdx.x & 7) * cpx + (blockIdx.x >> 3);
  const long arow0 = (long)(bid / nbx) * 128;
  const long brow0 = (long)(bid % nbx) * 128;

#define STAGE_G(k0_, buf_)                                                    \
  do {                                                                        \
    _Pragma("unroll")                                                         \
    for (int c_ = 0; c_ < 2; ++c_) {                                          \
      int off_ = (w << 11) + (c_ << 10) + (lane << 4);                        \
      int row_ = off_ >> 6;                                                   \
      int cbs_ = ((off_ >> 4) & 3) ^ ((row_ >> 1) & 3);                       \
      gload_lds16(A + (arow0 + row_) * (long)K + (k0_) + cbs_ * 8,            \
                  (char*)As[buf_] + off_);                                    \
      gload_lds16(Bw + (brow0 + row_) * (long)K + (k0_) + cbs_ * 8,           \
                  (char*)Bs[buf_] + off_);                                    \
    }                                                                         \
  } while (0)

  f32x4 acc[4][4];
#pragma unroll
  for (int i = 0; i < 4; ++i)
#pragma unroll
    for (int j = 0; j < 4; ++j) acc[i][j] = (f32x4){0.f, 0.f, 0.f, 0.f};

  const int T = K >> 5;
  int cur = 0;
  STAGE_G(0, 0);

  for (int t = 0; t < T; ++t) {
    if (t < T - 1) {
      STAGE_G((t + 1) << 5, cur ^ 1);
      asm volatile("s_waitcnt vmcnt(4)" ::: "memory");
    } else {
      asm volatile("s_waitcnt vmcnt(0)" ::: "memory");
    }
    __builtin_amdgcn_s_barrier();

    const int rb = g4 ^ ((r16 >> 1) & 3);
    bf16x8 af[4], bf[4];
#pragma unroll
    for (int mf = 0; mf < 4; ++mf)
      af[mf] = *(const bf16x8*)((const char*)As[cur] +
                                ((64 * wm + 16 * mf + r16) << 6) + (rb << 4));
#pragma unroll
    for (int nf = 0; nf < 4; ++nf)
      bf[nf] = *(const bf16x8*)((const char*)Bs[cur] +
                                ((64 * wn + 16 * nf + r16) << 6) + (rb << 4));
#pragma unroll
    for (int mf = 0; mf < 4; ++mf)
#pragma unroll
      for (int nf = 0; nf < 4; ++nf)
        acc[mf][nf] = MF(af[mf], bf[nf], acc[mf][nf]);
    asm volatile("" ::: "memory");
    __builtin_amdgcn_s_barrier();
    cur ^= 1;
  }
#undef STAGE_G

  const float qscale = 0.08838834764831845f;
#pragma unroll
  for (int mf = 0; mf < 4; ++mf) {
#pragma unroll
    for (int nf = 0; nf < 4; ++nf) {
#pragma unroll
      for (int i = 0; i < 4; ++i) {
        long row = arow0 + 64 * wm + 16 * mf + 4 * g4 + i;
        long col = brow0 + 64 * wn + 16 * nf + r16;
        float v = acc[mf][nf][i];
        if (EPI == 0) {
          Cf[row * N + col] = v;
        } else {
          int which = (int)(col >> 11);
          int h = ((int)col >> 7) & 15;
          int d = (int)col & 127;
          int b = (int)(row >> 11);
          int l = (int)row & 2047;
          long bhead = (long)(b * 16 + h);
          if (which == 0)
            Qo[(bhead * Lseq + l) * 128 + d] = f2bf(v * qscale);
          else if (which == 1)
            Ko[(bhead * Lseq + l) * 128 + d] = f2bf(v);
          else
            Vo[(bhead * 128 + d) * Lseq + l] = f2bf(v);
        }
      }
    }
  }
}

// ---------------------------------------------------------------------------
// Flash attention (causal) — round-12 version (swapped QK^T, in-lane softmax,
// defer-max). Works: ~70us.
// ---------------------------------------------------------------------------
__global__ __launch_bounds__(256, 2)
void attn_fwd(const unsigned short* __restrict__ Q,
              const unsigned short* __restrict__ K,
              const unsigned short* __restrict__ Vt,
              unsigned short* __restrict__ Y, int L) {
  const int D = 128;
  const int id = blockIdx.x;
  const int g = id & 7, kk = id >> 3;
  const int bh = (g << 2) + (kk >> 5);
  const int qt = 31 - (kk & 31);
  const int tid = threadIdx.x, lane = tid & 63, w = tid >> 6;
  const int g4 = lane >> 4, r16 = lane & 15;
  const int q0 = qt * 64;

  __shared__ unsigned short Klds[2 * 64 * 128];
  __shared__ unsigned short Vlds[2 * 128 * 64];
  __shared__ unsigned short P[4][16][64];
  __shared__ float corrS[4][16];
  __shared__ float lrunS[4][16];

  const unsigned short* Qh = Q + (long)bh * L * D;
  const unsigned short* Kh = K + (long)bh * L * D;
  const unsigned short* Vh = Vt + (long)bh * D * L;

#define STAGE_TILE(kt_, buf_)                                                 \
  do {                                                                        \
    const int kbase_ = (kt_) * 64;                                            \
    _Pragma("unroll")                                                         \
    for (int r_ = 0; r_ < 4; ++r_) {                                          \
      int off_ = (tid << 4) + (r_ << 12);                                     \
      int krow_ = off_ >> 8, kcb_ = (off_ >> 4) & 15;                         \
      int kcbs_ = kcb_ ^ (krow_ & 7);                                         \
      gload_lds16(Kh + (long)(kbase_ + krow_) * 128 + kcbs_ * 8,              \
                  (char*)Klds + (buf_)*16384 + (w << 10) + (r_ << 12));       \
      int vrow_ = off_ >> 7, vcb_ = (off_ >> 4) & 7;                          \
      int vcbs_ = vcb_ ^ (vrow_ & 7);                                         \
      gload_lds16(Vh + (long)vrow_ * L + kbase_ + vcbs_ * 8,                  \
                  (char*)Vlds + (buf_)*16384 + (w << 10) + (r_ << 12));       \
    }                                                                         \
  } while (0)

  bf16x8 qf[4];
  {
    long qrow = q0 + 16 * w + r16;
#pragma unroll
    for (int ks = 0; ks < 4; ++ks)
      qf[ks] = *(const bf16x8*)(Qh + qrow * D + ks * 32 + g4 * 8);
  }
  f32x4 o[8];
#pragma unroll
  for (int j = 0; j < 8; ++j) o[j] = (f32x4){0.f, 0.f, 0.f, 0.f};
  float mrun = -1e30f, lrun = 0.f;
  const int qg = q0 + 16 * w + r16;
  char* Pl = (char*)&P[w][0][0];

  int cur = 0;
  STAGE_TILE(0, 0);

  for (int kt = 0; kt <= qt; ++kt) {
    if (kt < qt) {
      STAGE_TILE(kt + 1, cur ^ 1);
      asm volatile("s_waitcnt vmcnt(8)" ::: "memory");
    } else {
      asm volatile("s_waitcnt vmcnt(0)" ::: "memory");
    }
    __builtin_amdgcn_s_barrier();

    const char* Kl = (const char*)Klds + cur * 16384;
    const char* Vl = (const char*)Vlds + cur * 16384;

    f32x4 s[4];
#pragma unroll
    for (int nf = 0; nf < 4; ++nf) s[nf] = (f32x4){0.f, 0.f, 0.f, 0.f};
#pragma unroll
    for (int ks = 0; ks < 4; ++ks) {
#pragma unroll
      for (int nf = 0; nf < 4; ++nf) {
        int row = 16 * nf + r16;
        bf16x8 kf = *(const bf16x8*)(Kl + row * 256 +
                                     (((ks * 4 + g4) ^ (row & 7)) << 4));
        s[nf] = MF(kf, qf[ks], s[nf]);
      }
    }

    const bool diag = (kt == qt);
    float rmax = -1e30f;
#pragma unroll
    for (int nf = 0; nf < 4; ++nf)
#pragma unroll
      for (int i = 0; i < 4; ++i) {
        float t = s[nf][i];
        if (diag && (kt * 64 + 16 * nf + 4 * g4 + i) > qg) t = -1e30f;
        s[nf][i] = t;
        rmax = fmaxf(rmax, t);
      }
    rmax = fmaxf(rmax, __shfl_xor(rmax, 16));
    rmax = fmaxf(rmax, __shfl_xor(rmax, 32));

    const bool full = __any(rmax > mrun + 8.0f);
    float corr = 1.f;
    if (full) {
      float mnew = fmaxf(mrun, rmax);
      corr = __expf(mrun - mnew);
      mrun = mnew;
      if (g4 == 0) corrS[w][r16] = corr;
    }

    float rs = 0.f;
#pragma unroll
    for (int nf = 0; nf < 4; ++nf) {
      float p0 = __expf(s[nf][0] - mrun);
      float p1 = __expf(s[nf][1] - mrun);
      float p2 = __expf(s[nf][2] - mrun);
      float p3 = __expf(s[nf][3] - mrun);
      rs += (p0 + p1) + (p2 + p3);
      ushort4 pw;
      pw.x = f2bf(p0); pw.y = f2bf(p1); pw.z = f2bf(p2); pw.w = f2bf(p3);
      *(ushort4*)(Pl + r16 * 128 + (((2 * nf + (g4 >> 1)) ^ (r16 & 7)) << 4) +
                  ((g4 & 1) << 3)) = pw;
    }
    rs += __shfl_xor(rs, 16);
    rs += __shfl_xor(rs, 32);
    lrun = lrun * corr + rs;

    if (full) {
#pragma unroll
      for (int i = 0; i < 4; ++i) {
        float cb = corrS[w][4 * g4 + i];
#pragma unroll
        for (int nf2 = 0; nf2 < 8; ++nf2) o[nf2][i] *= cb;
      }
    }

#pragma unroll
    for (int ks2 = 0; ks2 < 2; ++ks2) {
      bf16x8 pf = *(const bf16x8*)(Pl + r16 * 128 +
                                   (((ks2 * 4 + g4) ^ (r16 & 7)) << 4));
#pragma unroll
      for (int nf2 = 0; nf2 < 8; ++nf2) {
        int row = 16 * nf2 + r16;
        bf16x8 vf = *(const bf16x8*)(Vl + row * 128 +
                                     (((ks2 * 4 + g4) ^ (row & 7)) << 4));
        o[nf2] = MF(pf, vf, o[nf2]);
      }
    }
    FENCE;
    __builtin_amdgcn_s_barrier();
    cur ^= 1;
  }
#undef STAGE_TILE

  if (g4 == 0) lrunS[w][r16] = lrun;
  const int b = bh >> 4, h = bh & 15;
#pragma unroll
  for (int i = 0; i < 4; ++i) {
    float linv = 1.f / lrunS[w][4 * g4 + i];
#pragma unroll
    for (int nf2 = 0; nf2 < 8; ++nf2) {
      long row = (long)b * L + q0 + 16 * w + 4 * g4 + i;
      Y[row * 2048 + h * 128 + 16 * nf2 + r16] = f2bf(o[nf2][i] * linv);
    }
  }
}

// ---------------------------------------------------------------------------
extern "C" void kernel_launch(void* const* d_in, const int* in_sizes, int n_in,
                              void* d_out, int out_size, void* d_ws,
                              size_t ws_size, hipStream_t stream) {
  const float* x = (const float*)d_in[0];
  const float* wa = (const float*)d_in[1];
  const float* wp = (const float*)d_in[2];
  float* out = (float*)d_out;
  const int B = 2, L = 2048, C = 2048;
  const int M = B * L;  // 4096

  unsigned short* xb = (unsigned short*)d_ws;
  unsigned short* wab = xb + (size_t)M * C;
  unsigned short* wpb = wab + (size_t)3 * C * C;
  unsigned short* Qb = wpb + (size_t)C * C;
  unsigned short* Kb = Qb + (size_t)M * C;
  unsigned short* Vb = Kb + (size_t)M * C;
  unsigned short* Yb = Vb + (size_t)M * C;

  const int n1 = M * C / 4;
  const int n2 = n1 + 3 * C * C / 4;
  const int n4 = n2 + C * C / 4;
  cast_all<<<2048, 256, 0, stream>>>(x, wa, wp, xb, wab, wpb, n1, n2, n4);

  // qkv: 128x256, 32x32x16 MFMA, triple-buffered 1-phase-per-K-tile
  gemm8p<1><<<dim3(3 * C / 256, M / 128), 512, 0, stream>>>(
      xb, wab, nullptr, Qb, Kb, Vb, M, 3 * C, C, L);

  // attn: QBLK=64, 4 waves, 1024 blocks (2 blocks/CU)
  attn_fwd<<<1024, 256, 0, stream>>>(Qb, Kb, Vb, Yb, L);

  // proj: 2-phase 128^2, grid 512 blocks
  gemm_bt<0><<<(M / 128) * (C / 128), 256, 0, stream>>>(
      Yb, wpb, out, nullptr, nullptr, nullptr, M, C, C, L, C / 128);
}

// Round 21
// 289.322 us; speedup vs baseline: 1.0637x; 1.0637x over previous
//
#include <hip/hip_runtime.h>

typedef __attribute__((ext_vector_type(8))) short bf16x8;
typedef __attribute__((ext_vector_type(4))) float f32x4;

__device__ __forceinline__ unsigned short f2bf(float f) {
  unsigned int u = __float_as_uint(f);
  u += 0x7FFF + ((u >> 16) & 1);
  return (unsigned short)(u >> 16);
}

__device__ __forceinline__ void gload_lds16(const void* g, void* l) {
  __builtin_amdgcn_global_load_lds(
      (const __attribute__((address_space(1))) unsigned int*)g,
      (__attribute__((address_space(3))) unsigned int*)l,
      16, 0, 0);
}

#define MF(a, b, c) __builtin_amdgcn_mfma_f32_16x16x32_bf16((a), (b), (c), 0, 0, 0)
#define FENCE asm volatile("" ::: "memory")

// ---------------------------------------------------------------------------
// fused cast fp32 -> bf16 for x, w_attn, w_proj in one sweep
// ---------------------------------------------------------------------------
__global__ void cast_all(const float* __restrict__ x,
                         const float* __restrict__ wa,
                         const float* __restrict__ wp,
                         unsigned short* __restrict__ xb,
                         unsigned short* __restrict__ wab,
                         unsigned short* __restrict__ wpb,
                         int n1, int n2, int n4) {
  int stride = gridDim.x * blockDim.x;
  for (int i = blockIdx.x * blockDim.x + threadIdx.x; i < n4; i += stride) {
    const float4* src;
    ushort4* dst;
    int j;
    if (i < n1)      { src = (const float4*)x,  dst = (ushort4*)xb,  j = i; }
    else if (i < n2) { src = (const float4*)wa, dst = (ushort4*)wab, j = i - n1; }
    else             { src = (const float4*)wp, dst = (ushort4*)wpb, j = i - n2; }
    float4 v = src[j];
    ushort4 o;
    o.x = f2bf(v.x); o.y = f2bf(v.y); o.z = f2bf(v.z); o.w = f2bf(v.w);
    dst[j] = o;
  }
}

// ---------------------------------------------------------------------------
// 128x256 4-phase GEMM (v4, round-19 verbatim — 148.8us, conflicts 0).
// BK=64, counted vmcnt(4), 128B-row swizzle cb^=row&7, zero-tail grids.
// Used for BOTH qkv (EPI=1, grid 24x32 = 768 = 3 rounds) and proj
// (EPI=0, grid 8x32 = 256 = exactly 1 round).
// ---------------------------------------------------------------------------
template<int EPI>
__global__ __launch_bounds__(512, 2)
void gemm8p(const unsigned short* __restrict__ A,
            const unsigned short* __restrict__ Bw,
            float* __restrict__ Cf,
            unsigned short* __restrict__ Qo,
            unsigned short* __restrict__ Ko,
            unsigned short* __restrict__ Vo,
            int M, int N, int K, int Lseq) {
  __shared__ unsigned short Al[2][128 * 64];  // 2 x 16KB
  __shared__ unsigned short Bl[2][256 * 64];  // 2 x 32KB
  const int tid = threadIdx.x;
  const int lane = tid & 63, w = tid >> 6;
  const int wm = w >> 2, wn = w & 3;
  const int g4 = lane >> 4, r16 = lane & 15;
  const long arow0 = (long)blockIdx.y * 128;
  const long brow0 = (long)blockIdx.x * 256;

#define LDA(db, mf, ks)                                                       \
  (*(const bf16x8*)((const char*)&Al[db][0] +                                 \
                    ((wm * 64 + (mf)*16 + r16) << 7) +                        \
                    ((((ks)*4 + g4) ^ (r16 & 7)) << 4)))
#define LDB(db, nf, ks)                                                       \
  (*(const bf16x8*)((const char*)&Bl[db][0] +                                 \
                    ((wn * 64 + (nf)*16 + r16) << 7) +                        \
                    ((((ks)*4 + g4) ^ (r16 & 7)) << 4)))

#define STGA(db, kt)                                                          \
  do {                                                                        \
    _Pragma("unroll")                                                         \
    for (int c_ = 0; c_ < 2; ++c_) {                                          \
      int off_ = (c_ << 13) + (tid << 4);                                     \
      int row_ = off_ >> 7;                                                   \
      int cbs_ = ((off_ >> 4) & 7) ^ (row_ & 7);                              \
      gload_lds16(A + (arow0 + row_) * (long)K + ((kt) << 6) + cbs_ * 8,      \
                  (char*)&Al[db][0] + off_);                                  \
    }                                                                         \
  } while (0)
#define STGB(db, kt)                                                          \
  do {                                                                        \
    _Pragma("unroll")                                                         \
    for (int c_ = 0; c_ < 4; ++c_) {                                          \
      int off_ = (c_ << 13) + (tid << 4);                                     \
      int row_ = off_ >> 7;                                                   \
      int cbs_ = ((off_ >> 4) & 7) ^ (row_ & 7);                              \
      gload_lds16(Bw + (brow0 + row_) * (long)K + ((kt) << 6) + cbs_ * 8,     \
                  (char*)&Bl[db][0] + off_);                                  \
    }                                                                         \
  } while (0)

  f32x4 acc[4][4];
#pragma unroll
  for (int i = 0; i < 4; ++i)
#pragma unroll
    for (int j = 0; j < 4; ++j) acc[i][j] = (f32x4){0.f, 0.f, 0.f, 0.f};

  bf16x8 b00, b01, b10, b11, b20, b21, b30, b31;

#define LOADB(db)                                                             \
  do {                                                                        \
    b00 = LDB(db, 0, 0); b01 = LDB(db, 0, 1);                                 \
    b10 = LDB(db, 1, 0); b11 = LDB(db, 1, 1);                                 \
    b20 = LDB(db, 2, 0); b21 = LDB(db, 2, 1);                                 \
    b30 = LDB(db, 3, 0); b31 = LDB(db, 3, 1);                                 \
  } while (0)

#define PH(db, q, STAGE_STMT, VMSTMT)                                         \
  do {                                                                        \
    bf16x8 a00 = LDA(db, 2*(q), 0), a01 = LDA(db, 2*(q), 1);                  \
    bf16x8 a10 = LDA(db, 2*(q)+1, 0), a11 = LDA(db, 2*(q)+1, 1);              \
    STAGE_STMT;                                                               \
    VMSTMT;                                                                   \
    FENCE; __builtin_amdgcn_s_barrier(); FENCE;                               \
    __builtin_amdgcn_s_setprio(1);                                            \
    acc[2*(q)][0] = MF(a00, b00, acc[2*(q)][0]);                              \
    acc[2*(q)][0] = MF(a01, b01, acc[2*(q)][0]);                              \
    acc[2*(q)][1] = MF(a00, b10, acc[2*(q)][1]);                              \
    acc[2*(q)][1] = MF(a01, b11, acc[2*(q)][1]);                              \
    acc[2*(q)][2] = MF(a00, b20, acc[2*(q)][2]);                              \
    acc[2*(q)][2] = MF(a01, b21, acc[2*(q)][2]);                              \
    acc[2*(q)][3] = MF(a00, b30, acc[2*(q)][3]);                              \
    acc[2*(q)][3] = MF(a01, b31, acc[2*(q)][3]);                              \
    acc[2*(q)+1][0] = MF(a10, b00, acc[2*(q)+1][0]);                          \
    acc[2*(q)+1][0] = MF(a11, b01, acc[2*(q)+1][0]);                          \
    acc[2*(q)+1][1] = MF(a10, b10, acc[2*(q)+1][1]);                          \
    acc[2*(q)+1][1] = MF(a11, b11, acc[2*(q)+1][1]);                          \
    acc[2*(q)+1][2] = MF(a10, b20, acc[2*(q)+1][2]);                          \
    acc[2*(q)+1][2] = MF(a11, b21, acc[2*(q)+1][2]);                          \
    acc[2*(q)+1][3] = MF(a10, b30, acc[2*(q)+1][3]);                          \
    acc[2*(q)+1][3] = MF(a11, b31, acc[2*(q)+1][3]);                          \
    __builtin_amdgcn_s_setprio(0);                                            \
    FENCE; __builtin_amdgcn_s_barrier(); FENCE;                               \
  } while (0)

#define VM4 asm volatile("s_waitcnt vmcnt(4)" ::: "memory")

  const int NT = K >> 6;  // 32 K-tiles of 64
  STGB(0, 0); STGA(0, 0); STGB(1, 1);
  VM4;
  FENCE; __builtin_amdgcn_s_barrier(); FENCE;

  for (int i = 0; i < (NT >> 1); ++i) {
    const int t1 = 2 * i + 1;
    int t2 = 2 * i + 2; if (t2 > NT - 1) t2 = NT - 1;
    int t3 = 2 * i + 3; if (t3 > NT - 1) t3 = NT - 1;
    LOADB(0);
    PH(0, 0, STGA(1, t1), );        // ph1
    PH(0, 1, STGB(0, t2), VM4);     // ph2
    LOADB(1);
    PH(1, 0, STGA(0, t2), );        // ph3
    PH(1, 1, STGB(1, t3), VM4);     // ph4
  }
  asm volatile("s_waitcnt vmcnt(0)" ::: "memory");

  const float qscale = 0.08838834764831845f;  // 1/sqrt(128) folded into Q
#pragma unroll
  for (int mf = 0; mf < 4; ++mf) {
#pragma unroll
    for (int nf = 0; nf < 4; ++nf) {
#pragma unroll
      for (int i = 0; i < 4; ++i) {
        long row = arow0 + wm * 64 + mf * 16 + 4 * g4 + i;
        long col = brow0 + wn * 64 + nf * 16 + r16;
        float v = acc[mf][nf][i];
        if (EPI == 0) {
          Cf[row * N + col] = v;
        } else {
          int which = (int)(col >> 11);
          int h = ((int)col >> 7) & 15;
          int d = (int)col & 127;
          int b = (int)(row >> 11);
          int l = (int)row & 2047;
          long bhead = (long)(b * 16 + h);
          if (which == 0)
            Qo[(bhead * Lseq + l) * 128 + d] = f2bf(v * qscale);
          else if (which == 1)
            Ko[(bhead * Lseq + l) * 128 + d] = f2bf(v);
          else
            Vo[(bhead * 128 + d) * Lseq + l] = f2bf(v);
        }
      }
    }
  }
#undef LDA
#undef LDB
#undef STGA
#undef STGB
#undef PH
#undef LOADB
#undef VM4
}

// ---------------------------------------------------------------------------
// Flash attention (causal) — round-12 version (swapped QK^T, in-lane softmax,
// defer-max). Measured ~70us.
// ---------------------------------------------------------------------------
__global__ __launch_bounds__(256, 2)
void attn_fwd(const unsigned short* __restrict__ Q,
              const unsigned short* __restrict__ K,
              const unsigned short* __restrict__ Vt,
              unsigned short* __restrict__ Y, int L) {
  const int D = 128;
  const int id = blockIdx.x;
  const int g = id & 7, kk = id >> 3;
  const int bh = (g << 2) + (kk >> 5);
  const int qt = 31 - (kk & 31);
  const int tid = threadIdx.x, lane = tid & 63, w = tid >> 6;
  const int g4 = lane >> 4, r16 = lane & 15;
  const int q0 = qt * 64;

  __shared__ unsigned short Klds[2 * 64 * 128];
  __shared__ unsigned short Vlds[2 * 128 * 64];
  __shared__ unsigned short P[4][16][64];
  __shared__ float corrS[4][16];
  __shared__ float lrunS[4][16];

  const unsigned short* Qh = Q + (long)bh * L * D;
  const unsigned short* Kh = K + (long)bh * L * D;
  const unsigned short* Vh = Vt + (long)bh * D * L;

#define STAGE_TILE(kt_, buf_)                                                 \
  do {                                                                        \
    const int kbase_ = (kt_) * 64;                                            \
    _Pragma("unroll")                                                         \
    for (int r_ = 0; r_ < 4; ++r_) {                                          \
      int off_ = (tid << 4) + (r_ << 12);                                     \
      int krow_ = off_ >> 8, kcb_ = (off_ >> 4) & 15;                         \
      int kcbs_ = kcb_ ^ (krow_ & 7);                                         \
      gload_lds16(Kh + (long)(kbase_ + krow_) * 128 + kcbs_ * 8,              \
                  (char*)Klds + (buf_)*16384 + (w << 10) + (r_ << 12));       \
      int vrow_ = off_ >> 7, vcb_ = (off_ >> 4) & 7;                          \
      int vcbs_ = vcb_ ^ (vrow_ & 7);                                         \
      gload_lds16(Vh + (long)vrow_ * L + kbase_ + vcbs_ * 8,                  \
                  (char*)Vlds + (buf_)*16384 + (w << 10) + (r_ << 12));       \
    }                                                                         \
  } while (0)

  bf16x8 qf[4];
  {
    long qrow = q0 + 16 * w + r16;
#pragma unroll
    for (int ks = 0; ks < 4; ++ks)
      qf[ks] = *(const bf16x8*)(Qh + qrow * D + ks * 32 + g4 * 8);
  }
  f32x4 o[8];
#pragma unroll
  for (int j = 0; j < 8; ++j) o[j] = (f32x4){0.f, 0.f, 0.f, 0.f};
  float mrun = -1e30f, lrun = 0.f;
  const int qg = q0 + 16 * w + r16;
  char* Pl = (char*)&P[w][0][0];

  int cur = 0;
  STAGE_TILE(0, 0);

  for (int kt = 0; kt <= qt; ++kt) {
    if (kt < qt) {
      STAGE_TILE(kt + 1, cur ^ 1);
      asm volatile("s_waitcnt vmcnt(8)" ::: "memory");
    } else {
      asm volatile("s_waitcnt vmcnt(0)" ::: "memory");
    }
    __builtin_amdgcn_s_barrier();

    const char* Kl = (const char*)Klds + cur * 16384;
    const char* Vl = (const char*)Vlds + cur * 16384;

    f32x4 s[4];
#pragma unroll
    for (int nf = 0; nf < 4; ++nf) s[nf] = (f32x4){0.f, 0.f, 0.f, 0.f};
#pragma unroll
    for (int ks = 0; ks < 4; ++ks) {
#pragma unroll
      for (int nf = 0; nf < 4; ++nf) {
        int row = 16 * nf + r16;
        bf16x8 kf = *(const bf16x8*)(Kl + row * 256 +
                                     (((ks * 4 + g4) ^ (row & 7)) << 4));
        s[nf] = MF(kf, qf[ks], s[nf]);
      }
    }

    const bool diag = (kt == qt);
    float rmax = -1e30f;
#pragma unroll
    for (int nf = 0; nf < 4; ++nf)
#pragma unroll
      for (int i = 0; i < 4; ++i) {
        float t = s[nf][i];
        if (diag && (kt * 64 + 16 * nf + 4 * g4 + i) > qg) t = -1e30f;
        s[nf][i] = t;
        rmax = fmaxf(rmax, t);
      }
    rmax = fmaxf(rmax, __shfl_xor(rmax, 16));
    rmax = fmaxf(rmax, __shfl_xor(rmax, 32));

    const bool full = __any(rmax > mrun + 8.0f);
    float corr = 1.f;
    if (full) {
      float mnew = fmaxf(mrun, rmax);
      corr = __expf(mrun - mnew);
      mrun = mnew;
      if (g4 == 0) corrS[w][r16] = corr;
    }

    float rs = 0.f;
#pragma unroll
    for (int nf = 0; nf < 4; ++nf) {
      float p0 = __expf(s[nf][0] - mrun);
      float p1 = __expf(s[nf][1] - mrun);
      float p2 = __expf(s[nf][2] - mrun);
      float p3 = __expf(s[nf][3] - mrun);
      rs += (p0 + p1) + (p2 + p3);
      ushort4 pw;
      pw.x = f2bf(p0); pw.y = f2bf(p1); pw.z = f2bf(p2); pw.w = f2bf(p3);
      *(ushort4*)(Pl + r16 * 128 + (((2 * nf + (g4 >> 1)) ^ (r16 & 7)) << 4) +
                  ((g4 & 1) << 3)) = pw;
    }
    rs += __shfl_xor(rs, 16);
    rs += __shfl_xor(rs, 32);
    lrun = lrun * corr + rs;

    if (full) {
#pragma unroll
      for (int i = 0; i < 4; ++i) {
        float cb = corrS[w][4 * g4 + i];
#pragma unroll
        for (int nf2 = 0; nf2 < 8; ++nf2) o[nf2][i] *= cb;
      }
    }

#pragma unroll
    for (int ks2 = 0; ks2 < 2; ++ks2) {
      bf16x8 pf = *(const bf16x8*)(Pl + r16 * 128 +
                                   (((ks2 * 4 + g4) ^ (r16 & 7)) << 4));
#pragma unroll
      for (int nf2 = 0; nf2 < 8; ++nf2) {
        int row = 16 * nf2 + r16;
        bf16x8 vf = *(const bf16x8*)(Vl + row * 128 +
                                     (((ks2 * 4 + g4) ^ (row & 7)) << 4));
        o[nf2] = MF(pf, vf, o[nf2]);
      }
    }
    FENCE;
    __builtin_amdgcn_s_barrier();
    cur ^= 1;
  }
#undef STAGE_TILE

  if (g4 == 0) lrunS[w][r16] = lrun;
  const int b = bh >> 4, h = bh & 15;
#pragma unroll
  for (int i = 0; i < 4; ++i) {
    float linv = 1.f / lrunS[w][4 * g4 + i];
#pragma unroll
    for (int nf2 = 0; nf2 < 8; ++nf2) {
      long row = (long)b * L + q0 + 16 * w + 4 * g4 + i;
      Y[row * 2048 + h * 128 + 16 * nf2 + r16] = f2bf(o[nf2][i] * linv);
    }
  }
}

// ---------------------------------------------------------------------------
extern "C" void kernel_launch(void* const* d_in, const int* in_sizes, int n_in,
                              void* d_out, int out_size, void* d_ws,
                              size_t ws_size, hipStream_t stream) {
  const float* x = (const float*)d_in[0];
  const float* wa = (const float*)d_in[1];
  const float* wp = (const float*)d_in[2];
  float* out = (float*)d_out;
  const int B = 2, L = 2048, C = 2048;
  const int M = B * L;  // 4096

  unsigned short* xb = (unsigned short*)d_ws;
  unsigned short* wab = xb + (size_t)M * C;
  unsigned short* wpb = wab + (size_t)3 * C * C;
  unsigned short* Qb = wpb + (size_t)C * C;
  unsigned short* Kb = Qb + (size_t)M * C;
  unsigned short* Vb = Kb + (size_t)M * C;
  unsigned short* Yb = Vb + (size_t)M * C;

  const int n1 = M * C / 4;
  const int n2 = n1 + 3 * C * C / 4;
  const int n4 = n2 + C * C / 4;
  cast_all<<<2048, 256, 0, stream>>>(x, wa, wp, xb, wab, wpb, n1, n2, n4);

  // qkv: 128x256 4-phase BK=64, grid 24x32 = 768 blocks = exactly 3 rounds
  gemm8p<1><<<dim3(3 * C / 256, M / 128), 512, 0, stream>>>(
      xb, wab, nullptr, Qb, Kb, Vb, M, 3 * C, C, L);

  // attn: QBLK=64, 4 waves, 1024 blocks (2 blocks/CU)
  attn_fwd<<<1024, 256, 0, stream>>>(Qb, Kb, Vb, Yb, L);

  // proj: same v4 template, grid 8x32 = 256 blocks = exactly 1 round
  gemm8p<0><<<dim3(C / 256, M / 128), 512, 0, stream>>>(
      Yb, wpb, out, nullptr, nullptr, nullptr, M, C, C, L);
}

// Round 22
// 287.549 us; speedup vs baseline: 1.0703x; 1.0062x over previous
//
#include <hip/hip_runtime.h>

typedef __attribute__((ext_vector_type(8))) short bf16x8;
typedef __attribute__((ext_vector_type(4))) float f32x4;

__device__ __forceinline__ unsigned short f2bf(float f) {
  unsigned int u = __float_as_uint(f);
  u += 0x7FFF + ((u >> 16) & 1);
  return (unsigned short)(u >> 16);
}

__device__ __forceinline__ void gload_lds16(const void* g, void* l) {
  __builtin_amdgcn_global_load_lds(
      (const __attribute__((address_space(1))) unsigned int*)g,
      (__attribute__((address_space(3))) unsigned int*)l,
      16, 0, 0);
}

#define MF(a, b, c) __builtin_amdgcn_mfma_f32_16x16x32_bf16((a), (b), (c), 0, 0, 0)
#define FENCE asm volatile("" ::: "memory")
#define BAR do { FENCE; __builtin_amdgcn_s_barrier(); FENCE; } while (0)

// ---------------------------------------------------------------------------
// fused cast fp32 -> bf16 for x, w_attn, w_proj in one sweep
// ---------------------------------------------------------------------------
__global__ void cast_all(const float* __restrict__ x,
                         const float* __restrict__ wa,
                         const float* __restrict__ wp,
                         unsigned short* __restrict__ xb,
                         unsigned short* __restrict__ wab,
                         unsigned short* __restrict__ wpb,
                         int n1, int n2, int n4) {
  int stride = gridDim.x * blockDim.x;
  for (int i = blockIdx.x * blockDim.x + threadIdx.x; i < n4; i += stride) {
    const float4* src;
    ushort4* dst;
    int j;
    if (i < n1)      { src = (const float4*)x,  dst = (ushort4*)xb,  j = i; }
    else if (i < n2) { src = (const float4*)wa, dst = (ushort4*)wab, j = i - n1; }
    else             { src = (const float4*)wp, dst = (ushort4*)wpb, j = i - n2; }
    float4 v = src[j];
    ushort4 o;
    o.x = f2bf(v.x); o.y = f2bf(v.y); o.z = f2bf(v.z); o.w = f2bf(v.w);
    dst[j] = o;
  }
}

// ---------------------------------------------------------------------------
// 128x256 4-phase GEMM v6: v4's EXACT stage/vmcnt/barrier ledger, but all
// fragment ds_reads are issued at the TAIL of the previous phase (after its
// MFMAs, before its end barrier) into alternating X/Y register sets, so each
// phase head's MFMAs start with lgkm already drained and the LDS-read pipe
// overlaps the barrier + stage window.
// Tail-read validity audit (steady state, v4 ledger):
//   ph1-tail reads A.db0 q1  : db0.A holds t0, overwritten only at ph3  OK
//   ph2-tail reads B.db1,A.db1: staged ph1(prev A)/prologue, retired by
//                               ph2's vmcnt(4) BEFORE ph2's first barrier OK
//   ph3-tail reads A.db1 q1  : same region, stable until next-iter ph1   OK
//   ph4-tail reads B.db0,A.db0(t2): staged ph2/ph3, retired by ph4 vmcnt OK
// Overwrite audit: each STG target's last LDS read is >= 2 barriers prior
// (A.db1@ph1 last read prev ph3-tail; B.db0@ph2 last read prev ph4-tail;
//  A.db0@ph3 last read ph1-tail; B.db1@ph4 last read ph2-tail).
// Used for qkv (EPI=1, grid 24x32, 3 exact rounds) and proj (EPI=0, 8x32).
// ---------------------------------------------------------------------------
template<int EPI>
__global__ __launch_bounds__(512, 2)
void gemm8p(const unsigned short* __restrict__ A,
            const unsigned short* __restrict__ Bw,
            float* __restrict__ Cf,
            unsigned short* __restrict__ Qo,
            unsigned short* __restrict__ Ko,
            unsigned short* __restrict__ Vo,
            int M, int N, int K, int Lseq) {
  __shared__ unsigned short Al[2][128 * 64];  // 2 x 16KB
  __shared__ unsigned short Bl[2][256 * 64];  // 2 x 32KB
  const int tid = threadIdx.x;
  const int lane = tid & 63, w = tid >> 6;
  const int wm = w >> 2, wn = w & 3;
  const int g4 = lane >> 4, r16 = lane & 15;
  const long arow0 = (long)blockIdx.y * 128;
  const long brow0 = (long)blockIdx.x * 256;

#define LDA(db, mf, ks)                                                       \
  (*(const bf16x8*)((const char*)&Al[db][0] +                                 \
                    ((wm * 64 + (mf)*16 + r16) << 7) +                        \
                    ((((ks)*4 + g4) ^ (r16 & 7)) << 4)))
#define LDB(db, nf, ks)                                                       \
  (*(const bf16x8*)((const char*)&Bl[db][0] +                                 \
                    ((wn * 64 + (nf)*16 + r16) << 7) +                        \
                    ((((ks)*4 + g4) ^ (r16 & 7)) << 4)))

#define STGA(db, kt)                                                          \
  do {                                                                        \
    _Pragma("unroll")                                                         \
    for (int c_ = 0; c_ < 2; ++c_) {                                          \
      int off_ = (c_ << 13) + (tid << 4);                                     \
      int row_ = off_ >> 7;                                                   \
      int cbs_ = ((off_ >> 4) & 7) ^ (row_ & 7);                              \
      gload_lds16(A + (arow0 + row_) * (long)K + ((kt) << 6) + cbs_ * 8,      \
                  (char*)&Al[db][0] + off_);                                  \
    }                                                                         \
  } while (0)
#define STGB(db, kt)                                                          \
  do {                                                                        \
    _Pragma("unroll")                                                         \
    for (int c_ = 0; c_ < 4; ++c_) {                                          \
      int off_ = (c_ << 13) + (tid << 4);                                     \
      int row_ = off_ >> 7;                                                   \
      int cbs_ = ((off_ >> 4) & 7) ^ (row_ & 7);                              \
      gload_lds16(Bw + (brow0 + row_) * (long)K + ((kt) << 6) + cbs_ * 8,     \
                  (char*)&Bl[db][0] + off_);                                  \
    }                                                                         \
  } while (0)

  f32x4 acc[4][4];
#pragma unroll
  for (int i = 0; i < 4; ++i)
#pragma unroll
    for (int j = 0; j < 4; ++j) acc[i][j] = (f32x4){0.f, 0.f, 0.f, 0.f};

  bf16x8 b00, b01, b10, b11, b20, b21, b30, b31;
  bf16x8 x0, x1, x2, x3, y0, y1, y2, y3;

#define LOADB(db)                                                             \
  do {                                                                        \
    b00 = LDB(db, 0, 0); b01 = LDB(db, 0, 1);                                 \
    b10 = LDB(db, 1, 0); b11 = LDB(db, 1, 1);                                 \
    b20 = LDB(db, 2, 0); b21 = LDB(db, 2, 1);                                 \
    b30 = LDB(db, 3, 0); b31 = LDB(db, 3, 1);                                 \
  } while (0)

#define PREFA(d0, d1, d2, d3, db, q)                                          \
  do {                                                                        \
    d0 = LDA(db, 2*(q), 0);   d1 = LDA(db, 2*(q), 1);                         \
    d2 = LDA(db, 2*(q)+1, 0); d3 = LDA(db, 2*(q)+1, 1);                       \
  } while (0)

#define MFQ(q, A0, A1, A2, A3)                                                \
  do {                                                                        \
    __builtin_amdgcn_s_setprio(1);                                            \
    acc[2*(q)][0] = MF(A0, b00, acc[2*(q)][0]);                               \
    acc[2*(q)][0] = MF(A1, b01, acc[2*(q)][0]);                               \
    acc[2*(q)][1] = MF(A0, b10, acc[2*(q)][1]);                               \
    acc[2*(q)][1] = MF(A1, b11, acc[2*(q)][1]);                               \
    acc[2*(q)][2] = MF(A0, b20, acc[2*(q)][2]);                               \
    acc[2*(q)][2] = MF(A1, b21, acc[2*(q)][2]);                               \
    acc[2*(q)][3] = MF(A0, b30, acc[2*(q)][3]);                               \
    acc[2*(q)][3] = MF(A1, b31, acc[2*(q)][3]);                               \
    acc[2*(q)+1][0] = MF(A2, b00, acc[2*(q)+1][0]);                           \
    acc[2*(q)+1][0] = MF(A3, b01, acc[2*(q)+1][0]);                           \
    acc[2*(q)+1][1] = MF(A2, b10, acc[2*(q)+1][1]);                           \
    acc[2*(q)+1][1] = MF(A3, b11, acc[2*(q)+1][1]);                           \
    acc[2*(q)+1][2] = MF(A2, b20, acc[2*(q)+1][2]);                           \
    acc[2*(q)+1][2] = MF(A3, b21, acc[2*(q)+1][2]);                           \
    acc[2*(q)+1][3] = MF(A2, b30, acc[2*(q)+1][3]);                           \
    acc[2*(q)+1][3] = MF(A3, b31, acc[2*(q)+1][3]);                           \
    __builtin_amdgcn_s_setprio(0);                                            \
  } while (0)

#define VM4 asm volatile("s_waitcnt vmcnt(4)" ::: "memory")

  const int NT = K >> 6;  // 32 K-tiles of 64
  // prologue (v4 ledger): stage B0,A0,B1; vmcnt(4) retires B0+A0 (B1 in flight)
  STGB(0, 0); STGA(0, 0); STGB(1, 1);
  VM4;
  BAR;
  LOADB(0);
  PREFA(x0, x1, x2, x3, 0, 0);

  for (int i = 0; i < (NT >> 1); ++i) {
    const int t1 = 2 * i + 1;
    int t2 = 2 * i + 2; if (t2 > NT - 1) t2 = NT - 1;
    int t3 = 2 * i + 3; if (t3 > NT - 1) t3 = NT - 1;
    // ph1: compute db0,q0 (X); tail: prefetch db0,q1 -> Y
    STGA(1, t1);
    BAR;
    MFQ(0, x0, x1, x2, x3);
    PREFA(y0, y1, y2, y3, 0, 1);
    BAR;
    // ph2: compute db0,q1 (Y); tail: B(db1) + db1,q0 -> X
    STGB(0, t2);
    VM4;
    BAR;
    MFQ(1, y0, y1, y2, y3);
    LOADB(1);
    PREFA(x0, x1, x2, x3, 1, 0);
    BAR;
    // ph3: compute db1,q0 (X); tail: prefetch db1,q1 -> Y
    STGA(0, t2);
    BAR;
    MFQ(0, x0, x1, x2, x3);
    PREFA(y0, y1, y2, y3, 1, 1);
    BAR;
    // ph4: compute db1,q1 (Y); tail: B(db0,t2) + db0,q0(t2) -> X
    STGB(1, t3);
    VM4;
    BAR;
    MFQ(1, y0, y1, y2, y3);
    LOADB(0);
    PREFA(x0, x1, x2, x3, 0, 0);
    BAR;
  }
  asm volatile("s_waitcnt vmcnt(0)" ::: "memory");

  const float qscale = 0.08838834764831845f;  // 1/sqrt(128) folded into Q
#pragma unroll
  for (int mf = 0; mf < 4; ++mf) {
#pragma unroll
    for (int nf = 0; nf < 4; ++nf) {
#pragma unroll
      for (int i = 0; i < 4; ++i) {
        long row = arow0 + wm * 64 + mf * 16 + 4 * g4 + i;
        long col = brow0 + wn * 64 + nf * 16 + r16;
        float v = acc[mf][nf][i];
        if (EPI == 0) {
          Cf[row * N + col] = v;
        } else {
          int which = (int)(col >> 11);
          int h = ((int)col >> 7) & 15;
          int d = (int)col & 127;
          int b = (int)(row >> 11);
          int l = (int)row & 2047;
          long bhead = (long)(b * 16 + h);
          if (which == 0)
            Qo[(bhead * Lseq + l) * 128 + d] = f2bf(v * qscale);
          else if (which == 1)
            Ko[(bhead * Lseq + l) * 128 + d] = f2bf(v);
          else
            Vo[(bhead * 128 + d) * Lseq + l] = f2bf(v);
        }
      }
    }
  }
#undef LDA
#undef LDB
#undef STGA
#undef STGB
#undef LOADB
#undef PREFA
#undef MFQ
#undef VM4
}

// ---------------------------------------------------------------------------
// Flash attention (causal) — round-12 version (swapped QK^T, in-lane softmax,
// defer-max). Measured ~70us.
// ---------------------------------------------------------------------------
__global__ __launch_bounds__(256, 2)
void attn_fwd(const unsigned short* __restrict__ Q,
              const unsigned short* __restrict__ K,
              const unsigned short* __restrict__ Vt,
              unsigned short* __restrict__ Y, int L) {
  const int D = 128;
  const int id = blockIdx.x;
  const int g = id & 7, kk = id >> 3;
  const int bh = (g << 2) + (kk >> 5);
  const int qt = 31 - (kk & 31);
  const int tid = threadIdx.x, lane = tid & 63, w = tid >> 6;
  const int g4 = lane >> 4, r16 = lane & 15;
  const int q0 = qt * 64;

  __shared__ unsigned short Klds[2 * 64 * 128];
  __shared__ unsigned short Vlds[2 * 128 * 64];
  __shared__ unsigned short P[4][16][64];
  __shared__ float corrS[4][16];
  __shared__ float lrunS[4][16];

  const unsigned short* Qh = Q + (long)bh * L * D;
  const unsigned short* Kh = K + (long)bh * L * D;
  const unsigned short* Vh = Vt + (long)bh * D * L;

#define STAGE_TILE(kt_, buf_)                                                 \
  do {                                                                        \
    const int kbase_ = (kt_) * 64;                                            \
    _Pragma("unroll")                                                         \
    for (int r_ = 0; r_ < 4; ++r_) {                                          \
      int off_ = (tid << 4) + (r_ << 12);                                     \
      int krow_ = off_ >> 8, kcb_ = (off_ >> 4) & 15;                         \
      int kcbs_ = kcb_ ^ (krow_ & 7);                                         \
      gload_lds16(Kh + (long)(kbase_ + krow_) * 128 + kcbs_ * 8,              \
                  (char*)Klds + (buf_)*16384 + (w << 10) + (r_ << 12));       \
      int vrow_ = off_ >> 7, vcb_ = (off_ >> 4) & 7;                          \
      int vcbs_ = vcb_ ^ (vrow_ & 7);                                         \
      gload_lds16(Vh + (long)vrow_ * L + kbase_ + vcbs_ * 8,                  \
                  (char*)Vlds + (buf_)*16384 + (w << 10) + (r_ << 12));       \
    }                                                                         \
  } while (0)

  bf16x8 qf[4];
  {
    long qrow = q0 + 16 * w + r16;
#pragma unroll
    for (int ks = 0; ks < 4; ++ks)
      qf[ks] = *(const bf16x8*)(Qh + qrow * D + ks * 32 + g4 * 8);
  }
  f32x4 o[8];
#pragma unroll
  for (int j = 0; j < 8; ++j) o[j] = (f32x4){0.f, 0.f, 0.f, 0.f};
  float mrun = -1e30f, lrun = 0.f;
  const int qg = q0 + 16 * w + r16;
  char* Pl = (char*)&P[w][0][0];

  int cur = 0;
  STAGE_TILE(0, 0);

  for (int kt = 0; kt <= qt; ++kt) {
    if (kt < qt) {
      STAGE_TILE(kt + 1, cur ^ 1);
      asm volatile("s_waitcnt vmcnt(8)" ::: "memory");
    } else {
      asm volatile("s_waitcnt vmcnt(0)" ::: "memory");
    }
    __builtin_amdgcn_s_barrier();

    const char* Kl = (const char*)Klds + cur * 16384;
    const char* Vl = (const char*)Vlds + cur * 16384;

    f32x4 s[4];
#pragma unroll
    for (int nf = 0; nf < 4; ++nf) s[nf] = (f32x4){0.f, 0.f, 0.f, 0.f};
#pragma unroll
    for (int ks = 0; ks < 4; ++ks) {
#pragma unroll
      for (int nf = 0; nf < 4; ++nf) {
        int row = 16 * nf + r16;
        bf16x8 kf = *(const bf16x8*)(Kl + row * 256 +
                                     (((ks * 4 + g4) ^ (row & 7)) << 4));
        s[nf] = MF(kf, qf[ks], s[nf]);
      }
    }

    const bool diag = (kt == qt);
    float rmax = -1e30f;
#pragma unroll
    for (int nf = 0; nf < 4; ++nf)
#pragma unroll
      for (int i = 0; i < 4; ++i) {
        float t = s[nf][i];
        if (diag && (kt * 64 + 16 * nf + 4 * g4 + i) > qg) t = -1e30f;
        s[nf][i] = t;
        rmax = fmaxf(rmax, t);
      }
    rmax = fmaxf(rmax, __shfl_xor(rmax, 16));
    rmax = fmaxf(rmax, __shfl_xor(rmax, 32));

    const bool full = __any(rmax > mrun + 8.0f);
    float corr = 1.f;
    if (full) {
      float mnew = fmaxf(mrun, rmax);
      corr = __expf(mrun - mnew);
      mrun = mnew;
      if (g4 == 0) corrS[w][r16] = corr;
    }

    float rs = 0.f;
#pragma unroll
    for (int nf = 0; nf < 4; ++nf) {
      float p0 = __expf(s[nf][0] - mrun);
      float p1 = __expf(s[nf][1] - mrun);
      float p2 = __expf(s[nf][2] - mrun);
      float p3 = __expf(s[nf][3] - mrun);
      rs += (p0 + p1) + (p2 + p3);
      ushort4 pw;
      pw.x = f2bf(p0); pw.y = f2bf(p1); pw.z = f2bf(p2); pw.w = f2bf(p3);
      *(ushort4*)(Pl + r16 * 128 + (((2 * nf + (g4 >> 1)) ^ (r16 & 7)) << 4) +
                  ((g4 & 1) << 3)) = pw;
    }
    rs += __shfl_xor(rs, 16);
    rs += __shfl_xor(rs, 32);
    lrun = lrun * corr + rs;

    if (full) {
#pragma unroll
      for (int i = 0; i < 4; ++i) {
        float cb = corrS[w][4 * g4 + i];
#pragma unroll
        for (int nf2 = 0; nf2 < 8; ++nf2) o[nf2][i] *= cb;
      }
    }

#pragma unroll
    for (int ks2 = 0; ks2 < 2; ++ks2) {
      bf16x8 pf = *(const bf16x8*)(Pl + r16 * 128 +
                                   (((ks2 * 4 + g4) ^ (r16 & 7)) << 4));
#pragma unroll
      for (int nf2 = 0; nf2 < 8; ++nf2) {
        int row = 16 * nf2 + r16;
        bf16x8 vf = *(const bf16x8*)(Vl + row * 128 +
                                     (((ks2 * 4 + g4) ^ (row & 7)) << 4));
        o[nf2] = MF(pf, vf, o[nf2]);
      }
    }
    FENCE;
    __builtin_amdgcn_s_barrier();
    cur ^= 1;
  }
#undef STAGE_TILE

  if (g4 == 0) lrunS[w][r16] = lrun;
  const int b = bh >> 4, h = bh & 15;
#pragma unroll
  for (int i = 0; i < 4; ++i) {
    float linv = 1.f / lrunS[w][4 * g4 + i];
#pragma unroll
    for (int nf2 = 0; nf2 < 8; ++nf2) {
      long row = (long)b * L + q0 + 16 * w + 4 * g4 + i;
      Y[row * 2048 + h * 128 + 16 * nf2 + r16] = f2bf(o[nf2][i] * linv);
    }
  }
}

// ---------------------------------------------------------------------------
extern "C" void kernel_launch(void* const* d_in, const int* in_sizes, int n_in,
                              void* d_out, int out_size, void* d_ws,
                              size_t ws_size, hipStream_t stream) {
  const float* x = (const float*)d_in[0];
  const float* wa = (const float*)d_in[1];
  const float* wp = (const float*)d_in[2];
  float* out = (float*)d_out;
  const int B = 2, L = 2048, C = 2048;
  const int M = B * L;  // 4096

  unsigned short* xb = (unsigned short*)d_ws;
  unsigned short* wab = xb + (size_t)M * C;
  unsigned short* wpb = wab + (size_t)3 * C * C;
  unsigned short* Qb = wpb + (size_t)C * C;
  unsigned short* Kb = Qb + (size_t)M * C;
  unsigned short* Vb = Kb + (size_t)M * C;
  unsigned short* Yb = Vb + (size_t)M * C;

  const int n1 = M * C / 4;
  const int n2 = n1 + 3 * C * C / 4;
  const int n4 = n2 + C * C / 4;
  cast_all<<<2048, 256, 0, stream>>>(x, wa, wp, xb, wab, wpb, n1, n2, n4);

  // qkv: 128x256 4-phase BK=64 + tail-prefetch, grid 24x32 = 768 = 3 rounds
  gemm8p<1><<<dim3(3 * C / 256, M / 128), 512, 0, stream>>>(
      xb, wab, nullptr, Qb, Kb, Vb, M, 3 * C, C, L);

  // attn: QBLK=64, 4 waves, 1024 blocks (2 blocks/CU)
  attn_fwd<<<1024, 256, 0, stream>>>(Qb, Kb, Vb, Yb, L);

  // proj: same template, grid 8x32 = 256 blocks = exactly 1 round
  gemm8p<0><<<dim3(C / 256, M / 128), 512, 0, stream>>>(
      Yb, wpb, out, nullptr, nullptr, nullptr, M, C, C, L);
}